// Round 17
// baseline (100.650 us; speedup 1.0000x reference)
//
#include <hip/hip_runtime.h>
#include <math.h>

// Problem constants: B=2, S=2048, D=1024, H=16, DC=16, DH=64
typedef short short8 __attribute__((ext_vector_type(8)));
typedef short short4t __attribute__((ext_vector_type(4)));
typedef float f32x4  __attribute__((ext_vector_type(4)));

#define AS1 __attribute__((address_space(1)))
#define AS3 __attribute__((address_space(3)))

__device__ __forceinline__ unsigned cvt_pk_bf16(float lo, float hi) {
    unsigned r;
    asm("v_cvt_pk_bf16_f32 %0, %1, %2" : "=v"(r) : "v"(lo), "v"(hi));
    return r;
}
__device__ __forceinline__ unsigned f2bf_rne(float x) {
    unsigned u = __float_as_uint(x);
    return (u + 0x7fffu + ((u >> 16) & 1u)) >> 16;
}
__device__ __forceinline__ float exp2_fast(float x) {   // v_exp_f32 computes 2^x
    float r;
    asm("v_exp_f32 %0, %1" : "=v"(r) : "v"(x));
    return r;
}
// 16x16x16 bf16 MFMA (K=16): B-frag layout matches the 16x16 D-layout of the
// score MFMA, so P needs NO cross-lane redistribution before PV.
__device__ __forceinline__ f32x4 mfma_k16(short4t a, short4t b, f32x4 c) {
#if __has_builtin(__builtin_amdgcn_mfma_f32_16x16x16bf16_1k)
    return __builtin_amdgcn_mfma_f32_16x16x16bf16_1k(a, b, c, 0, 0, 0);
#else
    asm volatile("v_mfma_f32_16x16x16_bf16 %0, %1, %2, %0" : "+v"(c) : "v"(a), "v"(b));
    return c;
#endif
}

// ---------------------------------------------------------------------------
// Merged launch A: fp32->bf16 converts (blocks 0..3079) + zker (blocks 3080+).
// zker: z = coords @ Wc.T + bc, per head h with ch = -softplus(gamma_h)*log2e:
//   ZA[b,h,s,32] = [z(16), zsq, 1, 0...]          (keys / A-operand)
//   ZB[b,h,s,32] = [-2*ch*z(16), ch, ch*zsq, 0..] (queries / B-operand)
// => MFMA(ZA_k, ZB_q) = ch * (zsq_k + zsq_q - 2 z_k.z_q) = exp2 argument.
// ---------------------------------------------------------------------------
__global__ __launch_bounds__(256) void prep_all(const float* __restrict__ hidden,
                                                const float* __restrict__ Wv,
                                                const float* __restrict__ Wo,
                                                const float* __restrict__ Wn,
                                                const float* __restrict__ coords,
                                                const float* __restrict__ Wc,
                                                const float* __restrict__ bc,
                                                const float* __restrict__ gamma,
                                                short* __restrict__ hsb,
                                                short* __restrict__ Wvb,
                                                short* __restrict__ Wob,
                                                short* __restrict__ Wnb,
                                                short* __restrict__ ZA,
                                                short* __restrict__ ZB) {
    __shared__ float csh[16];
    if (blockIdx.x < 3080) {
        const int i = blockIdx.x * 256 + threadIdx.x;
        const float* src;
        short* dst;
        int ii;
        if (i < 524288)      { src = hidden; dst = hsb; ii = i; }
        else if (i < 655360) { src = Wv; dst = Wvb; ii = i - 524288; }
        else if (i < 786432) { src = Wo; dst = Wob; ii = i - 655360; }
        else                 { src = Wn; dst = Wnb; ii = i - 786432; }
        const float4 a = ((const float4*)src)[2 * ii];
        const float4 b = ((const float4*)src)[2 * ii + 1];
        uint4 r;
        r.x = cvt_pk_bf16(a.x, a.y);
        r.y = cvt_pk_bf16(a.z, a.w);
        r.z = cvt_pk_bf16(b.x, b.y);
        r.w = cvt_pk_bf16(b.z, b.w);
        ((uint4*)dst)[ii] = r;
        return;
    }
    const int bs = blockIdx.x - 3080;
    const int b = bs >> 11, s = bs & 2047;
    const int tid = threadIdx.x;
    if (tid < 16) csh[tid] = coords[(size_t)bs * 16 + tid];
    __syncthreads();
    float z = bc[tid];
#pragma unroll
    for (int k = 0; k < 16; k++) z = fmaf(csh[k], Wc[tid * 16 + k], z);
    const unsigned ub = f2bf_rne(z);
    const float zb = __uint_as_float(ub << 16);
    float sq = zb * zb;
    sq += __shfl_xor(sq, 1, 64);
    sq += __shfl_xor(sq, 2, 64);
    sq += __shfl_xor(sq, 4, 64);
    sq += __shfl_xor(sq, 8, 64);
    const int h = tid >> 4, c = tid & 15;
    const float gm = gamma[h];
    const float sp = fmaxf(gm, 0.f) + log1pf(__expf(-fabsf(gm)));  // softplus
    const float ch = -sp * 1.4426950408889634f;                    // -g*log2(e)
    const size_t row = ((size_t)(b * 16 + h) * 2048 + s) * 32;
    ZA[row + c] = (short)ub;
    ZA[row + 16 + c] = (c == 0) ? (short)f2bf_rne(sq)
                                : (c == 1 ? (short)0x3F80 : (short)0);
    ZB[row + c] = (short)f2bf_rne(-2.f * ch * zb);
    ZB[row + 16 + c] = (c == 0) ? (short)f2bf_rne(ch)
                                : (c == 1 ? (short)f2bf_rne(ch * sq) : (short)0);
}

// ---------------------------------------------------------------------------
// bf16 MFMA GEMM: C[m,n] = sum_k A[m,k]*W[n,k] + bias[n].  M=4096,N=1024,K=1024
// 128x64 tile, BK=64 (16 MFMAs per barrier), 4 waves (2x2 of 64x32), LDS
// double-buffer via global_load_lds w16, chunk-XOR swizzle via pre-swizzled
// global source (rule #21).  1D grid, bijective XCD swizzle.
// EPI=0: write V^T bf16 [b,h,dh,s] with the 8B-half swap (dh bit3).
//        Merged launch: blocks >= 512 run the coords GEMM (N=16) instead.
// EPI=1: fp32 row-major [m,n]
// ---------------------------------------------------------------------------
template <int EPI>
__global__ __launch_bounds__(256) void gemm_mfma(const short* __restrict__ A,
                                                 const short* __restrict__ W,
                                                 const float* __restrict__ bias,
                                                 void* __restrict__ Cout,
                                                 const short* __restrict__ Wnb,
                                                 const float* __restrict__ bn,
                                                 float* __restrict__ out1) {
    __shared__ short As[2][128][64];
    __shared__ short Bs[2][64][64];
    const int tid = threadIdx.x;
    const int wv = tid >> 6, l = tid & 63, g = l >> 4, qc = l & 15;

    if (EPI == 0 && blockIdx.x >= 512) {
        // ---- coords GEMM: updated_coords = A(bf16) @ Wnb.T + bn ----
        float* red = (float*)&As[0][0][0];   // reuse 4KB of the gemm LDS
        const int m0 = (blockIdx.x - 512) * 16;
        const int k0 = wv * 256;
        f32x4 acc = {};
#pragma unroll
        for (int kk = 0; kk < 256; kk += 32) {
            const short8 af = *(const short8*)(A + (size_t)(m0 + qc) * 1024 + k0 + kk + g * 8);
            const short8 bf = *(const short8*)(Wnb + (size_t)qc * 1024 + k0 + kk + g * 8);
            acc = __builtin_amdgcn_mfma_f32_16x16x32_bf16(af, bf, acc, 0, 0, 0);
        }
#pragma unroll
        for (int i2 = 0; i2 < 4; i2++) red[(wv * 256) + (g * 4 + i2) * 16 + qc] = acc[i2];
        __syncthreads();
        const int r = tid >> 4, c = tid & 15;
        const float s = red[r * 16 + c] + red[256 + r * 16 + c] +
                        red[512 + r * 16 + c] + red[768 + r * 16 + c] + bn[c];
        out1[(size_t)(m0 + r) * 16 + c] = s;
        return;
    }

    const int wm = wv >> 1, wn = wv & 1;
    const int lin = blockIdx.x;                       // 512 gemm blocks
    const int wid = (lin & 7) * 64 + (lin >> 3);      // bijective XCD swizzle
    const int Mb = (wid & 31) * 128, Nb = (wid >> 5) * 64;

    auto stage = [&](int buf, int k0) {
#pragma unroll
        for (int i = 0; i < 4; i++) {                    // A: 1024 chunks, 4/thread
            const int c = i * 256 + tid;
            const int r = c >> 3, jp = c & 7;
            const int js = jp ^ (r & 7);                 // pre-swizzled source
            const short* gsA = A + (size_t)(Mb + r) * 1024 + k0 + js * 8;
            short* ldsA = &As[buf][0][0] + (size_t)(i * 256 + wv * 64) * 8;
            __builtin_amdgcn_global_load_lds((const AS1 void*)gsA, (AS3 void*)ldsA, 16, 0, 0);
        }
#pragma unroll
        for (int i = 0; i < 2; i++) {                    // B: 512 chunks, 2/thread
            const int c = i * 256 + tid;
            const int r = c >> 3, jp = c & 7;
            const int js = jp ^ (r & 7);
            const short* gsB = W + (size_t)(Nb + r) * 1024 + k0 + js * 8;
            short* ldsB = &Bs[buf][0][0] + (size_t)(i * 256 + wv * 64) * 8;
            __builtin_amdgcn_global_load_lds((const AS1 void*)gsB, (AS3 void*)ldsB, 16, 0, 0);
        }
    };

    f32x4 acc[4][2] = {};
    stage(0, 0);
    __syncthreads();
    int cur = 0;
#pragma unroll 1
    for (int kb = 0; kb < 16; kb++) {
        if (kb < 15) stage(cur ^ 1, (kb + 1) * 64);
#pragma unroll
        for (int ks = 0; ks < 2; ks++) {
            const int cs = ((ks * 4 + g) ^ (qc & 7)) * 8;   // swizzled read slot
            short8 af[4], bfr[2];
#pragma unroll
            for (int mt = 0; mt < 4; mt++)
                af[mt] = *(const short8*)&As[cur][wm * 64 + mt * 16 + qc][cs];
#pragma unroll
            for (int nt = 0; nt < 2; nt++)
                bfr[nt] = *(const short8*)&Bs[cur][wn * 32 + nt * 16 + qc][cs];
#pragma unroll
            for (int mt = 0; mt < 4; mt++)
#pragma unroll
                for (int nt = 0; nt < 2; nt++)
                    acc[mt][nt] = __builtin_amdgcn_mfma_f32_16x16x32_bf16(af[mt], bfr[nt], acc[mt][nt], 0, 0, 0);
        }
        __syncthreads();
        cur ^= 1;
    }

    float bl[2];
#pragma unroll
    for (int nt = 0; nt < 2; nt++) bl[nt] = bias[Nb + wn * 32 + nt * 16 + qc];
#pragma unroll
    for (int mt = 0; mt < 4; mt++) {
#pragma unroll
        for (int nt = 0; nt < 2; nt++) {
            const int m0 = Mb + wm * 64 + mt * 16 + g * 4;
            const int n  = Nb + wn * 32 + nt * 16 + qc;
            f32x4 v = acc[mt][nt];
            v = v + bl[nt];
            if (EPI == 0) {
                const int bb = m0 >> 11, s0 = m0 & 2047;
                const int hh = n >> 6, dh = n & 63;
                const int s0x = s0 ^ (((n >> 3) & 1) << 2);   // 8B-half swap for dh bit3
                uint2 p2;
                p2.x = cvt_pk_bf16(v[0], v[1]);
                p2.y = cvt_pk_bf16(v[2], v[3]);
                *(uint2*)((short*)Cout + (size_t)((bb * 16 + hh) * 64 + dh) * 2048 + s0x) = p2;
            } else {
                float* C = (float*)Cout;
#pragma unroll
                for (int i = 0; i < 4; i++) C[(size_t)(m0 + i) * 1024 + n] = v[i];
            }
        }
    }
}

// ---------------------------------------------------------------------------
// Fused MFMA flash attention (v15 = v14 math, 32 q/wave):
//  * 4 waves x 32 q = 128 q/block, grid 512, 3 blocks/CU (launch_bounds 256,3).
//    zk/vf LDS reads are KEY-side — one set serves all 32 queries, HALVING
//    LDS-pipe demand per unit work vs 16 q/wave (v14's measured critical pipe:
//    ~2300 cyc LDS vs 1500 VALU vs 1100 MFMA per CU-iter).
//  * Conflict-free LDS layouts: chunk-permuted Z, half-swapped V (0 conflicts).
//  * T15 pkA/pkB named double-buffer (2-step unroll, rule #20-safe).
//  * l via ones-row K16 MFMA; all staging via global_load_lds (async DMA).
// ---------------------------------------------------------------------------
__global__ __launch_bounds__(256, 3) void attn_mfma15(const short* __restrict__ ZAg,
                                                      const short* __restrict__ ZBg,
                                                      const short* __restrict__ Vt,
                                                      short* __restrict__ AOb) {
    __shared__ short Vs[2][4096];   // V tile [j 0..7][dh 0..63] 16B slots, dbuf
    __shared__ short Zs[4][2048];   // Z tile, chunk-permuted, 4-deep ring
    const int tid = threadIdx.x;
    const int wv = tid >> 6, ln = tid & 63, g = ln >> 4, qc = ln & 15;
    const int lin = blockIdx.x;
    const int work = (lin & 7) * 64 + (lin >> 3);   // bijective, 512 % 8 == 0
    const int qb = work & 15, h = (work >> 4) & 15, b = work >> 8;
    const int bh = b * 16 + h;
    const int q0 = qb * 128 + wv * 32;              // this wave's 32 queries

    const short* ZAb = ZAg + (size_t)bh * (2048 * 32);
    const short* ZBb = ZBg + (size_t)bh * (2048 * 32);
    const short* Vb  = Vt  + (size_t)bh * (64 * 2048);

    short8 zq[2];
#pragma unroll
    for (int qt = 0; qt < 2; qt++)
        zq[qt] = *(const short8*)(ZBb + (size_t)(q0 + qt * 16 + qc) * 32 + g * 8);

    union { unsigned u[2]; short4t s4; } ones4;
    ones4.u[0] = ones4.u[1] = (qc == 0) ? 0x3F803F80u : 0u;  // A row 0 = ones

    f32x4 acc[2][4] = {};
    f32x4 accl[2] = {};

    // staging (thread-linear dests per rule #21): 2 V DMA + 1 Z DMA / thread
    const short* gvb = Vb + (size_t)ln * 2048 + wv * 8;
    short* lvd = &Vs[0][0] + (size_t)tid * 8;
    short* lzd = &Zs[0][0] + (size_t)tid * 8;
    // Z source permutation: thread tid stages LDS chunk tid; content is
    // (row = z_kt*16 + z_r, 8-short group z_g) of the tile.
    const int z_kt = tid >> 6, z_g = (tid >> 4) & 3, z_r = tid & 15;

    auto stageV = [&](int buf, int kb) {
        const short* gv = gvb + kb;
        short* lvb = lvd + buf * 4096;
        __builtin_amdgcn_global_load_lds((const AS1 void*)gv, (AS3 void*)lvb, 16, 0, 0);
        __builtin_amdgcn_global_load_lds((const AS1 void*)(gv + 32), (AS3 void*)(lvb + 2048), 16, 0, 0);
    };
    auto stageZ = [&](int buf, int kb) {
        const short* gz = ZAb + (size_t)(kb + z_kt * 16 + z_r) * 32 + z_g * 8;
        __builtin_amdgcn_global_load_lds((const AS1 void*)gz, (AS3 void*)(lzd + buf * 2048), 16, 0, 0);
    };

    // per-lane read bases (further offsets are compile-time immediates)
    const int vrd = (((g >> 1) * 64 + qc) * 8) + (((g & 1) ^ ((qc >> 3) & 1)) << 2);
    const int zrd = g * 128 + qc * 8;   // chunk g*16+qc of each 16-row group

    // S(tile)+exp2+pack for BOTH q-subtiles (zk read once, reused)
    auto computeP = [&](int zbuf, unsigned pko[2][4][2]) {
        const short* Zc = &Zs[0][0] + zbuf * 2048;
        short8 zk[4];
#pragma unroll
        for (int kt = 0; kt < 4; kt++)
            zk[kt] = *(const short8*)(Zc + zrd + kt * 512);
        const f32x4 z4 = {0.f, 0.f, 0.f, 0.f};
#pragma unroll
        for (int qt = 0; qt < 2; qt++)
#pragma unroll
            for (int kt = 0; kt < 4; kt++) {
                const f32x4 S = __builtin_amdgcn_mfma_f32_16x16x32_bf16(zk[kt], zq[qt], z4, 0, 0, 0);
                pko[qt][kt][0] = cvt_pk_bf16(exp2_fast(fminf(S[0], 0.f)), exp2_fast(fminf(S[1], 0.f)));
                pko[qt][kt][1] = cvt_pk_bf16(exp2_fast(fminf(S[2], 0.f)), exp2_fast(fminf(S[3], 0.f)));
            }
    };
    // PV + l for one tile: vf read once per kt, reused by both q-subtiles
    auto doPV = [&](int buf, unsigned pkk[2][4][2]) {
        const short* Vc = &Vs[buf][0];
        __builtin_amdgcn_s_setprio(1);
#pragma unroll
        for (int kt = 0; kt < 4; kt++) {
            short4t vf[4];
#pragma unroll
            for (int mt = 0; mt < 4; mt++)
                vf[mt] = *(const short4t*)(Vc + vrd + kt * 1024 + mt * 128);
#pragma unroll
            for (int qt = 0; qt < 2; qt++) {
                union { unsigned u[2]; short4t s4; } pb;
                pb.u[0] = pkk[qt][kt][0];
                pb.u[1] = pkk[qt][kt][1];
                accl[qt] = mfma_k16(ones4.s4, pb.s4, accl[qt]);
#pragma unroll
                for (int mt = 0; mt < 4; mt++)
                    acc[qt][mt] = mfma_k16(vf[mt], pb.s4, acc[qt][mt]);
            }
        }
        __builtin_amdgcn_s_setprio(0);
    };

    // prologue: V(0), Z(0), Z(1); compute pkA(tile 0)
    stageV(0, 0);
    stageZ(0, 0);
    stageZ(1, 64);
    __syncthreads();

    unsigned pkA[2][4][2], pkB[2][4][2];
    computeP(0, pkA);

    int cur = 0;
#pragma unroll 1
    for (int i = 0; i < 32; i += 2) {
        // ---- even step: consume pkA (tile i), produce pkB (tile i+1) ----
        if (i < 31) stageV(cur ^ 1, (i + 1) * 64);
        if (i < 30) stageZ((i + 2) & 3, (i + 2) * 64);
        computeP((i + 1) & 3, pkB);
        doPV(cur, pkA);
        __syncthreads();
        cur ^= 1;
        // ---- odd step: consume pkB (tile i+1), produce pkA (tile i+2) ----
        if (i + 1 < 31) stageV(cur ^ 1, (i + 2) * 64);
        if (i + 1 < 30) stageZ((i + 3) & 3, (i + 3) * 64);
        computeP((i + 2) & 3, pkA);   // last pair: stale slot, result unused
        doPV(cur, pkB);
        __syncthreads();
        cur ^= 1;
    }

    // epilogue: l sits at D(row0,col qc) = lane qc, reg 0 (per q-subtile)
#pragma unroll
    for (int qt = 0; qt < 2; qt++) {
        const float lv2 = __shfl(accl[qt][0], qc, 64);
        const float inv = 1.f / lv2;
        const size_t row = (size_t)(b * 2048 + q0 + qt * 16 + qc) * 1024 + h * 64;
#pragma unroll
        for (int mt = 0; mt < 4; mt++) {
            uint2 o;
            o.x = cvt_pk_bf16(acc[qt][mt][0] * inv, acc[qt][mt][1] * inv);
            o.y = cvt_pk_bf16(acc[qt][mt][2] * inv, acc[qt][mt][3] * inv);
            *(uint2*)(AOb + row + mt * 16 + g * 4) = o;
        }
    }
}

// ---------------------------------------------------------------------------
extern "C" void kernel_launch(void* const* d_in, const int* in_sizes, int n_in,
                              void* d_out, int out_size, void* d_ws, size_t ws_size,
                              hipStream_t stream) {
    (void)in_sizes; (void)n_in; (void)out_size; (void)ws_size;
    const float* hidden = (const float*)d_in[0];
    const float* coords = (const float*)d_in[1];
    const float* Wv = (const float*)d_in[2];
    const float* bv = (const float*)d_in[3];
    const float* Wc = (const float*)d_in[4];
    const float* bc = (const float*)d_in[5];
    const float* Wn = (const float*)d_in[6];
    const float* bn = (const float*)d_in[7];
    const float* Wo = (const float*)d_in[8];
    const float* bo = (const float*)d_in[9];
    const float* gamma = (const float*)d_in[10];

    char* wsb = (char*)d_ws;
    short* hsb = (short*)(wsb);                    // 0..8 MB  [4096,1024] bf16
    short* AOb = hsb;                              // aliases hsb (hsb dead after gemm<0>+coords)
    short* Wvb = (short*)(wsb + (8 << 20));        // 8..10 MB
    short* Wob = (short*)(wsb + (10 << 20));       // 10..12 MB
    short* Vt  = (short*)(wsb + (12 << 20));       // 12..20 MB [b,h,dh,s] bf16 (half-swapped)
    short* ZA  = (short*)(wsb + (20 << 20));       // 20..24 MB [b,h,s,32] bf16
    short* ZB  = (short*)(wsb + (24 << 20));       // 24..28 MB [b,h,s,32] bf16
    short* Wnb = (short*)(wsb + (28 << 20));       // 28 MB + 32 KB [16,1024] bf16

    float* out_hidden = (float*)d_out;             // [B,S,D]
    float* out_coords = out_hidden + 4194304;      // [B,S,CD]

    // A: converts + zker (independent inputs) in one launch
    prep_all<<<7176, 256, 0, stream>>>(hidden, Wv, Wo, Wn, coords, Wc, bc, gamma,
                                       hsb, Wvb, Wob, Wnb, ZA, ZB);
    // B: Wv GEMM (blocks 0..511) + coords GEMM (blocks 512..767)
    gemm_mfma<0><<<768, 256, 0, stream>>>(hsb, Wvb, bv, (void*)Vt, Wnb, bn, out_coords);
    attn_mfma15<<<512, 256, 0, stream>>>(ZA, ZB, Vt, AOb);
    gemm_mfma<1><<<512, 256, 0, stream>>>(AOb, Wob, bo, (void*)out_hidden, Wnb, bn, out_coords);
}

// Round 18
// 98.399 us; speedup vs baseline: 1.0229x; 1.0229x over previous
//
#include <hip/hip_runtime.h>
#include <math.h>

// Problem constants: B=2, S=2048, D=1024, H=16, DC=16, DH=64
typedef short short8 __attribute__((ext_vector_type(8)));
typedef short short4t __attribute__((ext_vector_type(4)));
typedef float f32x4  __attribute__((ext_vector_type(4)));

#define AS1 __attribute__((address_space(1)))
#define AS3 __attribute__((address_space(3)))

__device__ __forceinline__ unsigned cvt_pk_bf16(float lo, float hi) {
    unsigned r;
    asm("v_cvt_pk_bf16_f32 %0, %1, %2" : "=v"(r) : "v"(lo), "v"(hi));
    return r;
}
__device__ __forceinline__ unsigned f2bf_rne(float x) {
    unsigned u = __float_as_uint(x);
    return (u + 0x7fffu + ((u >> 16) & 1u)) >> 16;
}
__device__ __forceinline__ float exp2_fast(float x) {   // v_exp_f32 computes 2^x
    float r;
    asm("v_exp_f32 %0, %1" : "=v"(r) : "v"(x));
    return r;
}
// 16x16x16 bf16 MFMA (K=16): B-frag layout matches the 16x16 D-layout of the
// score MFMA, so P needs NO cross-lane redistribution before PV.
__device__ __forceinline__ f32x4 mfma_k16(short4t a, short4t b, f32x4 c) {
#if __has_builtin(__builtin_amdgcn_mfma_f32_16x16x16bf16_1k)
    return __builtin_amdgcn_mfma_f32_16x16x16bf16_1k(a, b, c, 0, 0, 0);
#else
    asm volatile("v_mfma_f32_16x16x16_bf16 %0, %1, %2, %0" : "+v"(c) : "v"(a), "v"(b));
    return c;
#endif
}

// ---------------------------------------------------------------------------
// Merged launch A: fp32->bf16 converts (blocks 0..3079) + zker (blocks 3080+).
// zker: z = coords @ Wc.T + bc, per head h with ch = -softplus(gamma_h)*log2e:
//   ZA[b,h,s,32] = [z(16), zsq, 1, 0...]          (keys / A-operand)
//   ZB[b,h,s,32] = [-2*ch*z(16), ch, ch*zsq, 0..] (queries / B-operand)
// => MFMA(ZA_k, ZB_q) = ch * (zsq_k + zsq_q - 2 z_k.z_q) = exp2 argument.
// ---------------------------------------------------------------------------
__global__ __launch_bounds__(256) void prep_all(const float* __restrict__ hidden,
                                                const float* __restrict__ Wv,
                                                const float* __restrict__ Wo,
                                                const float* __restrict__ Wn,
                                                const float* __restrict__ coords,
                                                const float* __restrict__ Wc,
                                                const float* __restrict__ bc,
                                                const float* __restrict__ gamma,
                                                short* __restrict__ hsb,
                                                short* __restrict__ Wvb,
                                                short* __restrict__ Wob,
                                                short* __restrict__ Wnb,
                                                short* __restrict__ ZA,
                                                short* __restrict__ ZB) {
    __shared__ float csh[16];
    if (blockIdx.x < 3080) {
        const int i = blockIdx.x * 256 + threadIdx.x;
        const float* src;
        short* dst;
        int ii;
        if (i < 524288)      { src = hidden; dst = hsb; ii = i; }
        else if (i < 655360) { src = Wv; dst = Wvb; ii = i - 524288; }
        else if (i < 786432) { src = Wo; dst = Wob; ii = i - 655360; }
        else                 { src = Wn; dst = Wnb; ii = i - 786432; }
        const float4 a = ((const float4*)src)[2 * ii];
        const float4 b = ((const float4*)src)[2 * ii + 1];
        uint4 r;
        r.x = cvt_pk_bf16(a.x, a.y);
        r.y = cvt_pk_bf16(a.z, a.w);
        r.z = cvt_pk_bf16(b.x, b.y);
        r.w = cvt_pk_bf16(b.z, b.w);
        ((uint4*)dst)[ii] = r;
        return;
    }
    const int bs = blockIdx.x - 3080;
    const int b = bs >> 11, s = bs & 2047;
    const int tid = threadIdx.x;
    if (tid < 16) csh[tid] = coords[(size_t)bs * 16 + tid];
    __syncthreads();
    float z = bc[tid];
#pragma unroll
    for (int k = 0; k < 16; k++) z = fmaf(csh[k], Wc[tid * 16 + k], z);
    const unsigned ub = f2bf_rne(z);
    const float zb = __uint_as_float(ub << 16);
    float sq = zb * zb;
    sq += __shfl_xor(sq, 1, 64);
    sq += __shfl_xor(sq, 2, 64);
    sq += __shfl_xor(sq, 4, 64);
    sq += __shfl_xor(sq, 8, 64);
    const int h = tid >> 4, c = tid & 15;
    const float gm = gamma[h];
    const float sp = fmaxf(gm, 0.f) + log1pf(__expf(-fabsf(gm)));  // softplus
    const float ch = -sp * 1.4426950408889634f;                    // -g*log2(e)
    const size_t row = ((size_t)(b * 16 + h) * 2048 + s) * 32;
    ZA[row + c] = (short)ub;
    ZA[row + 16 + c] = (c == 0) ? (short)f2bf_rne(sq)
                                : (c == 1 ? (short)0x3F80 : (short)0);
    ZB[row + c] = (short)f2bf_rne(-2.f * ch * zb);
    ZB[row + 16 + c] = (c == 0) ? (short)f2bf_rne(ch)
                                : (c == 1 ? (short)f2bf_rne(ch * sq) : (short)0);
}

// ---------------------------------------------------------------------------
// bf16 MFMA GEMM: C[m,n] = sum_k A[m,k]*W[n,k] + bias[n].  M=4096,N=1024,K=1024
// 128x64 tile, BK=64 (16 MFMAs per barrier), 4 waves (2x2 of 64x32), LDS
// double-buffer via global_load_lds w16, chunk-XOR swizzle via pre-swizzled
// global source (rule #21).  1D grid, bijective XCD swizzle.
// EPI=0: write V^T bf16 [b,h,dh,s] with the 8B-half swap (dh bit3).
//        Merged launch: blocks >= 512 run the coords GEMM (N=16) instead.
// EPI=1: fp32 row-major [m,n]
// ---------------------------------------------------------------------------
template <int EPI>
__global__ __launch_bounds__(256) void gemm_mfma(const short* __restrict__ A,
                                                 const short* __restrict__ W,
                                                 const float* __restrict__ bias,
                                                 void* __restrict__ Cout,
                                                 const short* __restrict__ Wnb,
                                                 const float* __restrict__ bn,
                                                 float* __restrict__ out1) {
    __shared__ short As[2][128][64];
    __shared__ short Bs[2][64][64];
    const int tid = threadIdx.x;
    const int wv = tid >> 6, l = tid & 63, g = l >> 4, qc = l & 15;

    if (EPI == 0 && blockIdx.x >= 512) {
        // ---- coords GEMM: updated_coords = A(bf16) @ Wnb.T + bn ----
        float* red = (float*)&As[0][0][0];   // reuse 4KB of the gemm LDS
        const int m0 = (blockIdx.x - 512) * 16;
        const int k0 = wv * 256;
        f32x4 acc = {};
#pragma unroll
        for (int kk = 0; kk < 256; kk += 32) {
            const short8 af = *(const short8*)(A + (size_t)(m0 + qc) * 1024 + k0 + kk + g * 8);
            const short8 bf = *(const short8*)(Wnb + (size_t)qc * 1024 + k0 + kk + g * 8);
            acc = __builtin_amdgcn_mfma_f32_16x16x32_bf16(af, bf, acc, 0, 0, 0);
        }
#pragma unroll
        for (int i2 = 0; i2 < 4; i2++) red[(wv * 256) + (g * 4 + i2) * 16 + qc] = acc[i2];
        __syncthreads();
        const int r = tid >> 4, c = tid & 15;
        const float s = red[r * 16 + c] + red[256 + r * 16 + c] +
                        red[512 + r * 16 + c] + red[768 + r * 16 + c] + bn[c];
        out1[(size_t)(m0 + r) * 16 + c] = s;
        return;
    }

    const int wm = wv >> 1, wn = wv & 1;
    const int lin = blockIdx.x;                       // 512 gemm blocks
    const int wid = (lin & 7) * 64 + (lin >> 3);      // bijective XCD swizzle
    const int Mb = (wid & 31) * 128, Nb = (wid >> 5) * 64;

    auto stage = [&](int buf, int k0) {
#pragma unroll
        for (int i = 0; i < 4; i++) {                    // A: 1024 chunks, 4/thread
            const int c = i * 256 + tid;
            const int r = c >> 3, jp = c & 7;
            const int js = jp ^ (r & 7);                 // pre-swizzled source
            const short* gsA = A + (size_t)(Mb + r) * 1024 + k0 + js * 8;
            short* ldsA = &As[buf][0][0] + (size_t)(i * 256 + wv * 64) * 8;
            __builtin_amdgcn_global_load_lds((const AS1 void*)gsA, (AS3 void*)ldsA, 16, 0, 0);
        }
#pragma unroll
        for (int i = 0; i < 2; i++) {                    // B: 512 chunks, 2/thread
            const int c = i * 256 + tid;
            const int r = c >> 3, jp = c & 7;
            const int js = jp ^ (r & 7);
            const short* gsB = W + (size_t)(Nb + r) * 1024 + k0 + js * 8;
            short* ldsB = &Bs[buf][0][0] + (size_t)(i * 256 + wv * 64) * 8;
            __builtin_amdgcn_global_load_lds((const AS1 void*)gsB, (AS3 void*)ldsB, 16, 0, 0);
        }
    };

    f32x4 acc[4][2] = {};
    stage(0, 0);
    __syncthreads();
    int cur = 0;
#pragma unroll 1
    for (int kb = 0; kb < 16; kb++) {
        if (kb < 15) stage(cur ^ 1, (kb + 1) * 64);
#pragma unroll
        for (int ks = 0; ks < 2; ks++) {
            const int cs = ((ks * 4 + g) ^ (qc & 7)) * 8;   // swizzled read slot
            short8 af[4], bfr[2];
#pragma unroll
            for (int mt = 0; mt < 4; mt++)
                af[mt] = *(const short8*)&As[cur][wm * 64 + mt * 16 + qc][cs];
#pragma unroll
            for (int nt = 0; nt < 2; nt++)
                bfr[nt] = *(const short8*)&Bs[cur][wn * 32 + nt * 16 + qc][cs];
#pragma unroll
            for (int mt = 0; mt < 4; mt++)
#pragma unroll
                for (int nt = 0; nt < 2; nt++)
                    acc[mt][nt] = __builtin_amdgcn_mfma_f32_16x16x32_bf16(af[mt], bfr[nt], acc[mt][nt], 0, 0, 0);
        }
        __syncthreads();
        cur ^= 1;
    }

    float bl[2];
#pragma unroll
    for (int nt = 0; nt < 2; nt++) bl[nt] = bias[Nb + wn * 32 + nt * 16 + qc];
#pragma unroll
    for (int mt = 0; mt < 4; mt++) {
#pragma unroll
        for (int nt = 0; nt < 2; nt++) {
            const int m0 = Mb + wm * 64 + mt * 16 + g * 4;
            const int n  = Nb + wn * 32 + nt * 16 + qc;
            f32x4 v = acc[mt][nt];
            v = v + bl[nt];
            if (EPI == 0) {
                const int bb = m0 >> 11, s0 = m0 & 2047;
                const int hh = n >> 6, dh = n & 63;
                const int s0x = s0 ^ (((n >> 3) & 1) << 2);   // 8B-half swap for dh bit3
                uint2 p2;
                p2.x = cvt_pk_bf16(v[0], v[1]);
                p2.y = cvt_pk_bf16(v[2], v[3]);
                *(uint2*)((short*)Cout + (size_t)((bb * 16 + hh) * 64 + dh) * 2048 + s0x) = p2;
            } else {
                float* C = (float*)Cout;
#pragma unroll
                for (int i = 0; i < 4; i++) C[(size_t)(m0 + i) * 1024 + n] = v[i];
            }
        }
    }
}

// ---------------------------------------------------------------------------
// Fused MFMA flash attention (v16 = v14 with KVBLK=128):
//  * 8 waves x 16 q = 128 q/block, grid 512 (same occupancy as v14: 2 blk/CU,
//    4 waves/SIMD) but key-tile DOUBLED to 128 -> barrier count and per-iter
//    stall overhead HALVED (v14 measured: ~640 cyc/iter stall above pipe work).
//  * V tile [j 0..15][dh 0..63] 16B slots (dbuf, 32KB); Z tile 128x32
//    chunk-permuted (4-ring, 32KB); total 64KB -> 2 blocks/CU unchanged.
//  * Staging: V 2 DMA/thread, Z exactly 1 DMA/thread (512 chunks/512 thr).
//  * Conflict-free layouts (chunk-permuted Z, half-swapped V); T15 pkA/pkB
//    2-step pipeline; l via ones-row K16 MFMA; all DMA via global_load_lds.
// ---------------------------------------------------------------------------
__global__ __launch_bounds__(512, 4) void attn_mfma16(const short* __restrict__ ZAg,
                                                      const short* __restrict__ ZBg,
                                                      const short* __restrict__ Vt,
                                                      short* __restrict__ AOb) {
    __shared__ short Vs[2][8192];   // V tile [j 0..15][dh 0..63] 16B slots, dbuf
    __shared__ short Zs[4][4096];   // Z tile 128x32, chunk-permuted, 4-ring
    const int tid = threadIdx.x;
    const int wv = tid >> 6, ln = tid & 63, g = ln >> 4, qc = ln & 15;
    const int lin = blockIdx.x;
    const int work = (lin & 7) * 64 + (lin >> 3);   // bijective, 512 % 8 == 0
    const int qb = work & 15, h = (work >> 4) & 15, b = work >> 8;
    const int bh = b * 16 + h;
    const int q0 = qb * 128 + wv * 16;

    const short* ZAb = ZAg + (size_t)bh * (2048 * 32);
    const short* ZBb = ZBg + (size_t)bh * (2048 * 32);
    const short* Vb  = Vt  + (size_t)bh * (64 * 2048);

    const short8 zq = *(const short8*)(ZBb + (size_t)(q0 + qc) * 32 + g * 8);

    union { unsigned u[2]; short4t s4; } ones4;
    ones4.u[0] = ones4.u[1] = (qc == 0) ? 0x3F803F80u : 0u;  // A row 0 = ones

    f32x4 acc[4] = {};
    f32x4 accl = {};

    // staging (thread-linear dests per rule #21):
    //  V: 1024 chunks (j=c>>6, dh=c&63); thread stages c=tid and c=tid+512
    //     (j offset +8 => global source +64 shorts).
    //  Z: 512 chunks; thread tid stages chunk tid; content is
    //     (row = (tid>>6)*16 + (tid&15), 8-short group (tid>>4)&3).
    const short* gvb = Vb + (size_t)(tid & 63) * 2048 + (tid >> 6) * 8;
    short* lvd = &Vs[0][0] + (size_t)tid * 8;
    short* lzd = &Zs[0][0] + (size_t)tid * 8;
    const int z_kt = tid >> 6, z_g = (tid >> 4) & 3, z_r = tid & 15;

    auto stageV = [&](int buf, int kb) {
        const short* gv = gvb + kb;
        short* lvb = lvd + buf * 8192;
        __builtin_amdgcn_global_load_lds((const AS1 void*)gv, (AS3 void*)lvb, 16, 0, 0);
        __builtin_amdgcn_global_load_lds((const AS1 void*)(gv + 64), (AS3 void*)(lvb + 4096), 16, 0, 0);
    };
    auto stageZ = [&](int buf, int kb) {
        const short* gz = ZAb + (size_t)(kb + z_kt * 16 + z_r) * 32 + z_g * 8;
        __builtin_amdgcn_global_load_lds((const AS1 void*)gz, (AS3 void*)(lzd + buf * 4096), 16, 0, 0);
    };

    // per-lane read bases (further offsets are compile-time immediates)
    const int vrd = (((g >> 1) * 64 + qc) * 8) + (((g & 1) ^ ((qc >> 3) & 1)) << 2);
    const int zrd = g * 128 + qc * 8;   // chunk g*16+qc of each 16-row group

    // S(tile)+exp2+pack over 8 kt groups (128 keys)
    auto computeP = [&](int zbuf, unsigned pko[8][2]) {
        const short* Zc = &Zs[0][0] + zbuf * 4096;
        const f32x4 z4 = {0.f, 0.f, 0.f, 0.f};
#pragma unroll
        for (int kt = 0; kt < 8; kt++) {
            const short8 zk = *(const short8*)(Zc + zrd + kt * 512);
            const f32x4 S = __builtin_amdgcn_mfma_f32_16x16x32_bf16(zk, zq, z4, 0, 0, 0);
            pko[kt][0] = cvt_pk_bf16(exp2_fast(fminf(S[0], 0.f)), exp2_fast(fminf(S[1], 0.f)));
            pko[kt][1] = cvt_pk_bf16(exp2_fast(fminf(S[2], 0.f)), exp2_fast(fminf(S[3], 0.f)));
        }
    };
    // PV + l for one 128-key tile
    auto doPV = [&](int buf, unsigned pkk[8][2]) {
        const short* Vc = &Vs[buf][0];
        __builtin_amdgcn_s_setprio(1);
#pragma unroll
        for (int kt = 0; kt < 8; kt++) {
            union { unsigned u[2]; short4t s4; } pb;
            pb.u[0] = pkk[kt][0];
            pb.u[1] = pkk[kt][1];
            accl = mfma_k16(ones4.s4, pb.s4, accl);
#pragma unroll
            for (int mt = 0; mt < 4; mt++)
                acc[mt] = mfma_k16(*(const short4t*)(Vc + vrd + kt * 1024 + mt * 128),
                                   pb.s4, acc[mt]);
        }
        __builtin_amdgcn_s_setprio(0);
    };

    // prologue: V(0), Z(0), Z(1); compute pkA(tile 0)
    stageV(0, 0);
    stageZ(0, 0);
    stageZ(1, 128);
    __syncthreads();

    unsigned pkA[8][2], pkB[8][2];
    computeP(0, pkA);

    int cur = 0;
#pragma unroll 1
    for (int i = 0; i < 16; i += 2) {
        // ---- even step: consume pkA (tile i), produce pkB (tile i+1) ----
        if (i < 15) stageV(cur ^ 1, (i + 1) * 128);
        if (i < 14) stageZ((i + 2) & 3, (i + 2) * 128);
        computeP((i + 1) & 3, pkB);
        doPV(cur, pkA);
        __syncthreads();
        cur ^= 1;
        // ---- odd step: consume pkB (tile i+1), produce pkA (tile i+2) ----
        if (i + 1 < 15) stageV(cur ^ 1, (i + 2) * 128);
        if (i + 1 < 14) stageZ((i + 3) & 3, (i + 3) * 128);
        computeP((i + 2) & 3, pkA);   // last pair: stale slot, result unused
        doPV(cur, pkB);
        __syncthreads();
        cur ^= 1;
    }

    // epilogue: l sits at D(row0,col qc) = lane qc, reg 0
    const float lv2 = __shfl(accl[0], qc, 64);
    const float inv = 1.f / lv2;
    const size_t row = (size_t)(b * 2048 + q0 + qc) * 1024 + h * 64;
#pragma unroll
    for (int mt = 0; mt < 4; mt++) {
        uint2 o;
        o.x = cvt_pk_bf16(acc[mt][0] * inv, acc[mt][1] * inv);
        o.y = cvt_pk_bf16(acc[mt][2] * inv, acc[mt][3] * inv);
        *(uint2*)(AOb + row + mt * 16 + g * 4) = o;
    }
}

// ---------------------------------------------------------------------------
extern "C" void kernel_launch(void* const* d_in, const int* in_sizes, int n_in,
                              void* d_out, int out_size, void* d_ws, size_t ws_size,
                              hipStream_t stream) {
    (void)in_sizes; (void)n_in; (void)out_size; (void)ws_size;
    const float* hidden = (const float*)d_in[0];
    const float* coords = (const float*)d_in[1];
    const float* Wv = (const float*)d_in[2];
    const float* bv = (const float*)d_in[3];
    const float* Wc = (const float*)d_in[4];
    const float* bc = (const float*)d_in[5];
    const float* Wn = (const float*)d_in[6];
    const float* bn = (const float*)d_in[7];
    const float* Wo = (const float*)d_in[8];
    const float* bo = (const float*)d_in[9];
    const float* gamma = (const float*)d_in[10];

    char* wsb = (char*)d_ws;
    short* hsb = (short*)(wsb);                    // 0..8 MB  [4096,1024] bf16
    short* AOb = hsb;                              // aliases hsb (hsb dead after gemm<0>+coords)
    short* Wvb = (short*)(wsb + (8 << 20));        // 8..10 MB
    short* Wob = (short*)(wsb + (10 << 20));       // 10..12 MB
    short* Vt  = (short*)(wsb + (12 << 20));       // 12..20 MB [b,h,dh,s] bf16 (half-swapped)
    short* ZA  = (short*)(wsb + (20 << 20));       // 20..24 MB [b,h,s,32] bf16
    short* ZB  = (short*)(wsb + (24 << 20));       // 24..28 MB [b,h,s,32] bf16
    short* Wnb = (short*)(wsb + (28 << 20));       // 28 MB + 32 KB [16,1024] bf16

    float* out_hidden = (float*)d_out;             // [B,S,D]
    float* out_coords = out_hidden + 4194304;      // [B,S,CD]

    // A: converts + zker (independent inputs) in one launch
    prep_all<<<7176, 256, 0, stream>>>(hidden, Wv, Wo, Wn, coords, Wc, bc, gamma,
                                       hsb, Wvb, Wob, Wnb, ZA, ZB);
    // B: Wv GEMM (blocks 0..511) + coords GEMM (blocks 512..767)
    gemm_mfma<0><<<768, 256, 0, stream>>>(hsb, Wvb, bv, (void*)Vt, Wnb, bn, out_coords);
    attn_mfma16<<<512, 512, 0, stream>>>(ZA, ZB, Vt, AOb);
    gemm_mfma<1><<<512, 256, 0, stream>>>(AOb, Wob, bo, (void*)out_hidden, Wnb, bn, out_coords);
}

// Round 19
// 93.078 us; speedup vs baseline: 1.0814x; 1.0572x over previous
//
#include <hip/hip_runtime.h>
#include <math.h>

// Problem constants: B=2, S=2048, D=1024, H=16, DC=16, DH=64
typedef short short8 __attribute__((ext_vector_type(8)));
typedef short short4t __attribute__((ext_vector_type(4)));
typedef float f32x4  __attribute__((ext_vector_type(4)));

#define AS1 __attribute__((address_space(1)))
#define AS3 __attribute__((address_space(3)))

__device__ __forceinline__ unsigned cvt_pk_bf16(float lo, float hi) {
    unsigned r;
    asm("v_cvt_pk_bf16_f32 %0, %1, %2" : "=v"(r) : "v"(lo), "v"(hi));
    return r;
}
__device__ __forceinline__ unsigned f2bf_rne(float x) {
    unsigned u = __float_as_uint(x);
    return (u + 0x7fffu + ((u >> 16) & 1u)) >> 16;
}
__device__ __forceinline__ float exp2_fast(float x) {   // v_exp_f32 computes 2^x
    float r;
    asm("v_exp_f32 %0, %1" : "=v"(r) : "v"(x));
    return r;
}
// 16x16x16 bf16 MFMA (K=16): B-frag layout matches the 16x16 D-layout of the
// score MFMA, so P needs NO cross-lane redistribution before PV.
__device__ __forceinline__ f32x4 mfma_k16(short4t a, short4t b, f32x4 c) {
#if __has_builtin(__builtin_amdgcn_mfma_f32_16x16x16bf16_1k)
    return __builtin_amdgcn_mfma_f32_16x16x16bf16_1k(a, b, c, 0, 0, 0);
#else
    asm volatile("v_mfma_f32_16x16x16_bf16 %0, %1, %2, %0" : "+v"(c) : "v"(a), "v"(b));
    return c;
#endif
}

// ---------------------------------------------------------------------------
// Merged launch A: fp32->bf16 converts (blocks 0..3079) + zker (blocks 3080+).
// zker: z = coords @ Wc.T + bc, per head h with ch = -softplus(gamma_h)*log2e:
//   ZA[b,h,s,32] = [z(16), zsq, 1, 0...]          (keys / A-operand)
//   ZB[b,h,s,32] = [-2*ch*z(16), ch, ch*zsq, 0..] (queries / B-operand)
// => MFMA(ZA_k, ZB_q) = ch * (zsq_k + zsq_q - 2 z_k.z_q) = exp2 argument.
// ---------------------------------------------------------------------------
__global__ __launch_bounds__(256) void prep_all(const float* __restrict__ hidden,
                                                const float* __restrict__ Wv,
                                                const float* __restrict__ Wo,
                                                const float* __restrict__ Wn,
                                                const float* __restrict__ coords,
                                                const float* __restrict__ Wc,
                                                const float* __restrict__ bc,
                                                const float* __restrict__ gamma,
                                                short* __restrict__ hsb,
                                                short* __restrict__ Wvb,
                                                short* __restrict__ Wob,
                                                short* __restrict__ Wnb,
                                                short* __restrict__ ZA,
                                                short* __restrict__ ZB) {
    __shared__ float csh[16];
    if (blockIdx.x < 3080) {
        const int i = blockIdx.x * 256 + threadIdx.x;
        const float* src;
        short* dst;
        int ii;
        if (i < 524288)      { src = hidden; dst = hsb; ii = i; }
        else if (i < 655360) { src = Wv; dst = Wvb; ii = i - 524288; }
        else if (i < 786432) { src = Wo; dst = Wob; ii = i - 655360; }
        else                 { src = Wn; dst = Wnb; ii = i - 786432; }
        const float4 a = ((const float4*)src)[2 * ii];
        const float4 b = ((const float4*)src)[2 * ii + 1];
        uint4 r;
        r.x = cvt_pk_bf16(a.x, a.y);
        r.y = cvt_pk_bf16(a.z, a.w);
        r.z = cvt_pk_bf16(b.x, b.y);
        r.w = cvt_pk_bf16(b.z, b.w);
        ((uint4*)dst)[ii] = r;
        return;
    }
    const int bs = blockIdx.x - 3080;
    const int b = bs >> 11, s = bs & 2047;
    const int tid = threadIdx.x;
    if (tid < 16) csh[tid] = coords[(size_t)bs * 16 + tid];
    __syncthreads();
    float z = bc[tid];
#pragma unroll
    for (int k = 0; k < 16; k++) z = fmaf(csh[k], Wc[tid * 16 + k], z);
    const unsigned ub = f2bf_rne(z);
    const float zb = __uint_as_float(ub << 16);
    float sq = zb * zb;
    sq += __shfl_xor(sq, 1, 64);
    sq += __shfl_xor(sq, 2, 64);
    sq += __shfl_xor(sq, 4, 64);
    sq += __shfl_xor(sq, 8, 64);
    const int h = tid >> 4, c = tid & 15;
    const float gm = gamma[h];
    const float sp = fmaxf(gm, 0.f) + log1pf(__expf(-fabsf(gm)));  // softplus
    const float ch = -sp * 1.4426950408889634f;                    // -g*log2(e)
    const size_t row = ((size_t)(b * 16 + h) * 2048 + s) * 32;
    ZA[row + c] = (short)ub;
    ZA[row + 16 + c] = (c == 0) ? (short)f2bf_rne(sq)
                                : (c == 1 ? (short)0x3F80 : (short)0);
    ZB[row + c] = (short)f2bf_rne(-2.f * ch * zb);
    ZB[row + 16 + c] = (c == 0) ? (short)f2bf_rne(ch)
                                : (c == 1 ? (short)f2bf_rne(ch * sq) : (short)0);
}

// ---------------------------------------------------------------------------
// bf16 MFMA GEMM: C[m,n] = sum_k A[m,k]*W[n,k] + bias[n].  M=4096,N=1024,K=1024
// 128x64 tile, BK=64 (16 MFMAs per barrier), 4 waves (2x2 of 64x32), LDS
// double-buffer via global_load_lds w16, chunk-XOR swizzle via pre-swizzled
// global source (rule #21).  1D grid, bijective XCD swizzle.
// EPI=0: write V^T bf16 [b,h,dh,s] with the 8B-half swap (dh bit3).
//        Merged launch: blocks >= 512 run the coords GEMM (N=16) instead.
// EPI=1: fp32 row-major [m,n]
// ---------------------------------------------------------------------------
template <int EPI>
__global__ __launch_bounds__(256) void gemm_mfma(const short* __restrict__ A,
                                                 const short* __restrict__ W,
                                                 const float* __restrict__ bias,
                                                 void* __restrict__ Cout,
                                                 const short* __restrict__ Wnb,
                                                 const float* __restrict__ bn,
                                                 float* __restrict__ out1) {
    __shared__ short As[2][128][64];
    __shared__ short Bs[2][64][64];
    const int tid = threadIdx.x;
    const int wv = tid >> 6, l = tid & 63, g = l >> 4, qc = l & 15;

    if (EPI == 0 && blockIdx.x >= 512) {
        // ---- coords GEMM: updated_coords = A(bf16) @ Wnb.T + bn ----
        float* red = (float*)&As[0][0][0];   // reuse 4KB of the gemm LDS
        const int m0 = (blockIdx.x - 512) * 16;
        const int k0 = wv * 256;
        f32x4 acc = {};
#pragma unroll
        for (int kk = 0; kk < 256; kk += 32) {
            const short8 af = *(const short8*)(A + (size_t)(m0 + qc) * 1024 + k0 + kk + g * 8);
            const short8 bf = *(const short8*)(Wnb + (size_t)qc * 1024 + k0 + kk + g * 8);
            acc = __builtin_amdgcn_mfma_f32_16x16x32_bf16(af, bf, acc, 0, 0, 0);
        }
#pragma unroll
        for (int i2 = 0; i2 < 4; i2++) red[(wv * 256) + (g * 4 + i2) * 16 + qc] = acc[i2];
        __syncthreads();
        const int r = tid >> 4, c = tid & 15;
        const float s = red[r * 16 + c] + red[256 + r * 16 + c] +
                        red[512 + r * 16 + c] + red[768 + r * 16 + c] + bn[c];
        out1[(size_t)(m0 + r) * 16 + c] = s;
        return;
    }

    const int wm = wv >> 1, wn = wv & 1;
    const int lin = blockIdx.x;                       // 512 gemm blocks
    const int wid = (lin & 7) * 64 + (lin >> 3);      // bijective XCD swizzle
    const int Mb = (wid & 31) * 128, Nb = (wid >> 5) * 64;

    auto stage = [&](int buf, int k0) {
#pragma unroll
        for (int i = 0; i < 4; i++) {                    // A: 1024 chunks, 4/thread
            const int c = i * 256 + tid;
            const int r = c >> 3, jp = c & 7;
            const int js = jp ^ (r & 7);                 // pre-swizzled source
            const short* gsA = A + (size_t)(Mb + r) * 1024 + k0 + js * 8;
            short* ldsA = &As[buf][0][0] + (size_t)(i * 256 + wv * 64) * 8;
            __builtin_amdgcn_global_load_lds((const AS1 void*)gsA, (AS3 void*)ldsA, 16, 0, 0);
        }
#pragma unroll
        for (int i = 0; i < 2; i++) {                    // B: 512 chunks, 2/thread
            const int c = i * 256 + tid;
            const int r = c >> 3, jp = c & 7;
            const int js = jp ^ (r & 7);
            const short* gsB = W + (size_t)(Nb + r) * 1024 + k0 + js * 8;
            short* ldsB = &Bs[buf][0][0] + (size_t)(i * 256 + wv * 64) * 8;
            __builtin_amdgcn_global_load_lds((const AS1 void*)gsB, (AS3 void*)ldsB, 16, 0, 0);
        }
    };

    f32x4 acc[4][2] = {};
    stage(0, 0);
    __syncthreads();
    int cur = 0;
#pragma unroll 1
    for (int kb = 0; kb < 16; kb++) {
        if (kb < 15) stage(cur ^ 1, (kb + 1) * 64);
#pragma unroll
        for (int ks = 0; ks < 2; ks++) {
            const int cs = ((ks * 4 + g) ^ (qc & 7)) * 8;   // swizzled read slot
            short8 af[4], bfr[2];
#pragma unroll
            for (int mt = 0; mt < 4; mt++)
                af[mt] = *(const short8*)&As[cur][wm * 64 + mt * 16 + qc][cs];
#pragma unroll
            for (int nt = 0; nt < 2; nt++)
                bfr[nt] = *(const short8*)&Bs[cur][wn * 32 + nt * 16 + qc][cs];
#pragma unroll
            for (int mt = 0; mt < 4; mt++)
#pragma unroll
                for (int nt = 0; nt < 2; nt++)
                    acc[mt][nt] = __builtin_amdgcn_mfma_f32_16x16x32_bf16(af[mt], bfr[nt], acc[mt][nt], 0, 0, 0);
        }
        __syncthreads();
        cur ^= 1;
    }

    float bl[2];
#pragma unroll
    for (int nt = 0; nt < 2; nt++) bl[nt] = bias[Nb + wn * 32 + nt * 16 + qc];
#pragma unroll
    for (int mt = 0; mt < 4; mt++) {
#pragma unroll
        for (int nt = 0; nt < 2; nt++) {
            const int m0 = Mb + wm * 64 + mt * 16 + g * 4;
            const int n  = Nb + wn * 32 + nt * 16 + qc;
            f32x4 v = acc[mt][nt];
            v = v + bl[nt];
            if (EPI == 0) {
                const int bb = m0 >> 11, s0 = m0 & 2047;
                const int hh = n >> 6, dh = n & 63;
                const int s0x = s0 ^ (((n >> 3) & 1) << 2);   // 8B-half swap for dh bit3
                uint2 p2;
                p2.x = cvt_pk_bf16(v[0], v[1]);
                p2.y = cvt_pk_bf16(v[2], v[3]);
                *(uint2*)((short*)Cout + (size_t)((bb * 16 + hh) * 64 + dh) * 2048 + s0x) = p2;
            } else {
                float* C = (float*)Cout;
#pragma unroll
                for (int i = 0; i < 4; i++) C[(size_t)(m0 + i) * 1024 + n] = v[i];
            }
        }
    }
}

// ---------------------------------------------------------------------------
// Fused MFMA flash attention (v17 = round-16 v14, clamp dropped):
//  * 128 q/block (8 waves x 16 q), grid 512, 2 blocks/CU, 4 waves/SIMD.
//  * Scores S <= 0 mathematically (S = -g*dv, g>=0, dv>=0); bf16 rounding
//    admits S <= ~+0.01 -> p <= 1.007, normalized out by l.  Dropping the
//    fminf clamp removes 16 VALU ops/iter/wave from the measured-critical
//    pipe (round-9 empirically validated: absmax 0.0377 < 0.054 threshold).
//  * Conflict-free LDS layouts: chunk-permuted Z, half-swapped V (0 conflicts).
//  * T15 pk pipeline with pkA/pkB named double-buffer (2-step unroll).
//  * l via ones-row K16 MFMA; all staging via global_load_lds.
// ---------------------------------------------------------------------------
__global__ __launch_bounds__(512, 4) void attn_mfma17(const short* __restrict__ ZAg,
                                                      const short* __restrict__ ZBg,
                                                      const short* __restrict__ Vt,
                                                      short* __restrict__ AOb) {
    __shared__ short Vs[2][4096];   // V tile [j 0..7][dh 0..63] 16B slots, dbuf
    __shared__ short Zs[4][2048];   // Z tile, chunk-permuted, 4-deep ring
    const int tid = threadIdx.x;
    const int wv = tid >> 6, ln = tid & 63, g = ln >> 4, qc = ln & 15;
    const int lin = blockIdx.x;
    const int work = (lin & 7) * 64 + (lin >> 3);   // bijective, 512 % 8 == 0
    const int qb = work & 15, h = (work >> 4) & 15, b = work >> 8;
    const int bh = b * 16 + h;
    const int q0 = qb * 128 + wv * 16;

    const short* ZAb = ZAg + (size_t)bh * (2048 * 32);
    const short* ZBb = ZBg + (size_t)bh * (2048 * 32);
    const short* Vb  = Vt  + (size_t)bh * (64 * 2048);

    const short8 zq = *(const short8*)(ZBb + (size_t)(q0 + qc) * 32 + g * 8);

    union { unsigned u[2]; short4t s4; } ones4;
    ones4.u[0] = ones4.u[1] = (qc == 0) ? 0x3F803F80u : 0u;  // A row 0 = ones

    f32x4 acc[4] = {};
    f32x4 accl = {};

    // staging (thread-linear dests per rule #21): V chunk tid (j=tid>>6,
    // dh=tid&63), one per thread; Z chunk tid for tid<256 (v12's permutation).
    const short* gvb = Vb + (size_t)(tid & 63) * 2048 + (tid >> 6) * 8;
    short* lvd = &Vs[0][0] + (size_t)tid * 8;
    short* lzd = &Zs[0][0] + (size_t)tid * 8;
    const int z_kt = tid >> 6, z_g = (tid >> 4) & 3, z_r = tid & 15;

    auto stageV = [&](int buf, int kb) {
        __builtin_amdgcn_global_load_lds((const AS1 void*)(gvb + kb),
                                         (AS3 void*)(lvd + buf * 4096), 16, 0, 0);
    };
    auto stageZ = [&](int buf, int kb) {
        if (tid < 256) {   // waves 0..3 (wave-uniform branch)
            const short* gz = ZAb + (size_t)(kb + z_kt * 16 + z_r) * 32 + z_g * 8;
            __builtin_amdgcn_global_load_lds((const AS1 void*)gz,
                                             (AS3 void*)(lzd + buf * 2048), 16, 0, 0);
        }
    };

    // per-lane read bases (further offsets are compile-time immediates)
    const int vrd = (((g >> 1) * 64 + qc) * 8) + (((g & 1) ^ ((qc >> 3) & 1)) << 2);
    const int zrd = g * 128 + qc * 8;   // chunk g*16+qc of each 16-row group

    auto computeP = [&](int zbuf, unsigned pko[4][2]) {
        const short* Zc = &Zs[0][0] + zbuf * 2048;
        short8 zk[4];
#pragma unroll
        for (int kt = 0; kt < 4; kt++)
            zk[kt] = *(const short8*)(Zc + zrd + kt * 512);
        const f32x4 z4 = {0.f, 0.f, 0.f, 0.f};
#pragma unroll
        for (int kt = 0; kt < 4; kt++) {
            const f32x4 S = __builtin_amdgcn_mfma_f32_16x16x32_bf16(zk[kt], zq, z4, 0, 0, 0);
            pko[kt][0] = cvt_pk_bf16(exp2_fast(S[0]), exp2_fast(S[1]));
            pko[kt][1] = cvt_pk_bf16(exp2_fast(S[2]), exp2_fast(S[3]));
        }
    };
    auto doPV = [&](int buf, unsigned pkk[4][2]) {
        const short* Vc = &Vs[buf][0];
        __builtin_amdgcn_s_setprio(1);
#pragma unroll
        for (int kt = 0; kt < 4; kt++) {
            union { unsigned u[2]; short4t s4; } pb;
            pb.u[0] = pkk[kt][0];
            pb.u[1] = pkk[kt][1];
            accl = mfma_k16(ones4.s4, pb.s4, accl);
#pragma unroll
            for (int mt = 0; mt < 4; mt++)
                acc[mt] = mfma_k16(*(const short4t*)(Vc + vrd + kt * 1024 + mt * 128),
                                   pb.s4, acc[mt]);
        }
        __builtin_amdgcn_s_setprio(0);
    };

    // prologue: V(0), Z(0), Z(1); compute pkA(tile 0)
    stageV(0, 0);
    stageZ(0, 0);
    stageZ(1, 64);
    __syncthreads();

    unsigned pkA[4][2], pkB[4][2];
    computeP(0, pkA);

    int cur = 0;
#pragma unroll 1
    for (int i = 0; i < 32; i += 2) {
        // ---- even step: consume pkA (tile i), produce pkB (tile i+1) ----
        if (i < 31) stageV(cur ^ 1, (i + 1) * 64);
        if (i < 30) stageZ((i + 2) & 3, (i + 2) * 64);
        computeP((i + 1) & 3, pkB);
        doPV(cur, pkA);
        __syncthreads();
        cur ^= 1;
        // ---- odd step: consume pkB (tile i+1), produce pkA (tile i+2) ----
        if (i + 1 < 31) stageV(cur ^ 1, (i + 2) * 64);
        if (i + 1 < 30) stageZ((i + 3) & 3, (i + 3) * 64);
        computeP((i + 2) & 3, pkA);   // last pair: stale slot, result unused
        doPV(cur, pkB);
        __syncthreads();
        cur ^= 1;
    }

    // epilogue: l sits at D(row0,col qc) = lane qc, reg 0
    const float lv2 = __shfl(accl[0], qc, 64);
    const float inv = 1.f / lv2;
    const size_t row = (size_t)(b * 2048 + q0 + qc) * 1024 + h * 64;
#pragma unroll
    for (int mt = 0; mt < 4; mt++) {
        uint2 o;
        o.x = cvt_pk_bf16(acc[mt][0] * inv, acc[mt][1] * inv);
        o.y = cvt_pk_bf16(acc[mt][2] * inv, acc[mt][3] * inv);
        *(uint2*)(AOb + row + mt * 16 + g * 4) = o;
    }
}

// ---------------------------------------------------------------------------
extern "C" void kernel_launch(void* const* d_in, const int* in_sizes, int n_in,
                              void* d_out, int out_size, void* d_ws, size_t ws_size,
                              hipStream_t stream) {
    (void)in_sizes; (void)n_in; (void)out_size; (void)ws_size;
    const float* hidden = (const float*)d_in[0];
    const float* coords = (const float*)d_in[1];
    const float* Wv = (const float*)d_in[2];
    const float* bv = (const float*)d_in[3];
    const float* Wc = (const float*)d_in[4];
    const float* bc = (const float*)d_in[5];
    const float* Wn = (const float*)d_in[6];
    const float* bn = (const float*)d_in[7];
    const float* Wo = (const float*)d_in[8];
    const float* bo = (const float*)d_in[9];
    const float* gamma = (const float*)d_in[10];

    char* wsb = (char*)d_ws;
    short* hsb = (short*)(wsb);                    // 0..8 MB  [4096,1024] bf16
    short* AOb = hsb;                              // aliases hsb (hsb dead after gemm<0>+coords)
    short* Wvb = (short*)(wsb + (8 << 20));        // 8..10 MB
    short* Wob = (short*)(wsb + (10 << 20));       // 10..12 MB
    short* Vt  = (short*)(wsb + (12 << 20));       // 12..20 MB [b,h,dh,s] bf16 (half-swapped)
    short* ZA  = (short*)(wsb + (20 << 20));       // 20..24 MB [b,h,s,32] bf16
    short* ZB  = (short*)(wsb + (24 << 20));       // 24..28 MB [b,h,s,32] bf16
    short* Wnb = (short*)(wsb + (28 << 20));       // 28 MB + 32 KB [16,1024] bf16

    float* out_hidden = (float*)d_out;             // [B,S,D]
    float* out_coords = out_hidden + 4194304;      // [B,S,CD]

    // A: converts + zker (independent inputs) in one launch
    prep_all<<<7176, 256, 0, stream>>>(hidden, Wv, Wo, Wn, coords, Wc, bc, gamma,
                                       hsb, Wvb, Wob, Wnb, ZA, ZB);
    // B: Wv GEMM (blocks 0..511) + coords GEMM (blocks 512..767)
    gemm_mfma<0><<<768, 256, 0, stream>>>(hsb, Wvb, bv, (void*)Vt, Wnb, bn, out_coords);
    attn_mfma17<<<512, 512, 0, stream>>>(ZA, ZB, Vt, AOb);
    gemm_mfma<1><<<512, 256, 0, stream>>>(AOb, Wob, bo, (void*)out_hidden, Wnb, bn, out_coords);
}